// Round 2
// baseline (19388.858 us; speedup 1.0000x reference)
//
#include <hip/hip_runtime.h>
#include <cstdint>
#include <cstddef>

// Autoregressive LSTM cell with softmax feedback. B=256, T=512, D=512, N=64.
// Persistent (non-cooperative) kernel: 128 blocks x 256 threads.
//   group g = rows [g*64, g*64+64); block covers d-tile dt (16 d x 4 gates = 64 gate-cols).
// Per step: y-phase (softmax(h_{t-1}) via MFMA, redundant per block) -> syncthreads ->
//           gates GEMM K=1088 (x | h | y) -> LSTM elementwise -> h write (double-buffered)
//           -> ONE timeout-guarded global barrier per group per step.
// Numerics: fp16 hi/lo split operands (exact to ~2^-22), 3-pass MFMA, fp32 accum/state.

typedef _Float16 f16x8 __attribute__((ext_vector_type(8)));
typedef float f32x4 __attribute__((ext_vector_type(4)));

#define MFMA16(a, b, c_) __builtin_amdgcn_mfma_f32_16x16x32_f16((a), (b), (c_), 0, 0, 0)

__device__ __forceinline__ void cvt8(const float4 a, const float4 b, f16x8& hi, f16x8& lo) {
  float v[8] = {a.x, a.y, a.z, a.w, b.x, b.y, b.z, b.w};
#pragma unroll
  for (int j = 0; j < 8; ++j) {
    _Float16 h = (_Float16)v[j];
    hi[j] = h;
    lo[j] = (_Float16)(v[j] - (float)h);
  }
}

// ---------------------------------------------------------------------------
// prep: fragment-ordered fp16 hi|lo buffers. Slot map sigma(h,j)=4h+(j&3)+16*(j>>2)
// (same bijection used for A and B fragments -> MFMA result independent of HW k-order).
// Per (unit, ki): 64 lanes x (hi8|lo8) = 32B/lane.
// ---------------------------------------------------------------------------
template <bool XPRE>
__global__ void prep_kernel(const float* __restrict__ x, const float* __restrict__ init_h,
                            const float* __restrict__ W_ih, const float* __restrict__ b_ih,
                            const float* __restrict__ W_hh, const float* __restrict__ b_hh,
                            const float* __restrict__ W_lin,
                            _Float16* __restrict__ xs, _Float16* __restrict__ wf,
                            _Float16* __restrict__ wl, _Float16* __restrict__ hs,
                            float* __restrict__ bias, int* __restrict__ bar) {
  const int NX = XPRE ? 256 * 512 * 16 * 4 : 0;  // (row,t,ki,h) -> 8 elements
  const int NWF = 128 * 34 * 64;                 // (ct,ki,l)
  const int NWL = 4 * 16 * 64;
  const int NH = 256 * 16 * 4;
  int tid = blockIdx.x * 256 + threadIdx.x;

  if (XPRE && tid < NX) {
    int h = tid & 3, ki = (tid >> 2) & 15, t = (tid >> 6) & 511, row = tid >> 15;
    const float* s = x + (((size_t)row * 512 + t) * 512 + ki * 32 + 4 * h);
    float4 a = *(const float4*)s, b = *(const float4*)(s + 16);
    f16x8 hi, lo;
    cvt8(a, b, hi, lo);
    _Float16* d = xs + ((((size_t)row * 512 + t) * 16 + ki) * 64 + h * 16);
    *(f16x8*)d = hi;
    *(f16x8*)(d + 8) = lo;
    return;
  }
  int u = tid - NX;
  if (u >= 0 && u < NWF) {
    int l = u & 63, u2 = u >> 6;
    int ki = u2 % 34, ct = u2 / 34;
    int col = ct * 16 + (l & 15), h = l >> 4;
    int k = ki * 32 + 4 * h;
    float4 a, b;
    if (k < 512) {
      const float* p = W_ih + (size_t)col * 576;
      a = *(const float4*)(p + k);
      b = *(const float4*)(p + k + 16);
    } else if (k < 1024) {
      const float* p = W_hh + (size_t)col * 512;
      a = *(const float4*)(p + k - 512);
      b = *(const float4*)(p + k - 512 + 16);
    } else {
      const float* p = W_ih + (size_t)col * 576 + 512;
      a = *(const float4*)(p + k - 1024);
      b = *(const float4*)(p + k - 1024 + 16);
    }
    f16x8 hi, lo;
    cvt8(a, b, hi, lo);
    _Float16* d = wf + (((size_t)ct * 34 + ki) * 64 + l) * 16;
    *(f16x8*)d = hi;
    *(f16x8*)(d + 8) = lo;
    return;
  }
  u -= NWF;
  if (u >= 0 && u < NWL) {
    int l = u & 63, u2 = u >> 6;
    int ki = u2 & 15, ct = u2 >> 4;
    int col = ct * 16 + (l & 15), h = l >> 4;
    int k = ki * 32 + 4 * h;
    const float* p = W_lin + (size_t)col * 512;
    float4 a = *(const float4*)(p + k), b = *(const float4*)(p + k + 16);
    f16x8 hi, lo;
    cvt8(a, b, hi, lo);
    _Float16* d = wl + (((size_t)ct * 16 + ki) * 64 + l) * 16;
    *(f16x8*)d = hi;
    *(f16x8*)(d + 8) = lo;
    return;
  }
  u -= NWL;
  if (u >= 0 && u < NH) {
    int h = u & 3, ki = (u >> 2) & 15, row = u >> 6;
    const float* s = init_h + ((size_t)row * 512 + ki * 32 + 4 * h);
    float4 a = *(const float4*)s, b = *(const float4*)(s + 16);
    f16x8 hi, lo;
    cvt8(a, b, hi, lo);
    _Float16* d = hs + (((size_t)row * 16 + ki) * 64 + h * 16);  // buffer 0
    *(f16x8*)d = hi;
    *(f16x8*)(d + 8) = lo;
    return;
  }
  u -= NH;
  if (u >= 0 && u < 2048) {
    bias[u] = b_ih[u] + b_hh[u];
    return;
  }
  u -= 2048;
  if (u >= 0 && u < 8) bar[u] = 0;
}

// Timeout-guarded per-group barrier. Counter monotonic; target = 32*(t+1).
__device__ __forceinline__ void gbar(int* cnt, int* abortf, int target, int* s_ab) {
  __syncthreads();  // drains this block's stores (compiler emits vmcnt(0) before s_barrier)
  if (threadIdx.x == 0) {
    __hip_atomic_fetch_add(cnt, 1, __ATOMIC_RELEASE, __HIP_MEMORY_SCOPE_AGENT);
    int it = 0, a = 0;
    while (__hip_atomic_load(cnt, __ATOMIC_ACQUIRE, __HIP_MEMORY_SCOPE_AGENT) < target) {
      __builtin_amdgcn_s_sleep(8);
      if (++it > 150000) {  // ~40-70ms: visible failure, never a hang
        a = 1;
        __hip_atomic_store(abortf, 1, __ATOMIC_RELAXED, __HIP_MEMORY_SCOPE_AGENT);
        break;
      }
      if ((it & 255) == 0 &&
          __hip_atomic_load(abortf, __ATOMIC_RELAXED, __HIP_MEMORY_SCOPE_AGENT) != 0) {
        a = 1;
        break;
      }
    }
    *s_ab = a;
  }
  __syncthreads();
}

#define GATES_MFMA(KI)                                                         \
  {                                                                            \
    const _Float16* B0 = wf0 + (size_t)(KI)*1024;                              \
    const _Float16* B1 = wf1 + (size_t)(KI)*1024;                              \
    const _Float16* B2 = wf2 + (size_t)(KI)*1024;                              \
    const _Float16* B3 = wf3 + (size_t)(KI)*1024;                              \
    f16x8 b0h = *(const f16x8*)B0, b1h = *(const f16x8*)B1;                    \
    f16x8 b2h = *(const f16x8*)B2, b3h = *(const f16x8*)B3;                    \
    a0 = MFMA16(ah, b0h, a0);                                                  \
    a1 = MFMA16(ah, b1h, a1);                                                  \
    a2 = MFMA16(ah, b2h, a2);                                                  \
    a3 = MFMA16(ah, b3h, a3);                                                  \
    a0 = MFMA16(al, b0h, a0);                                                  \
    a1 = MFMA16(al, b1h, a1);                                                  \
    a2 = MFMA16(al, b2h, a2);                                                  \
    a3 = MFMA16(al, b3h, a3);                                                  \
    f16x8 b0l = *(const f16x8*)(B0 + 8), b1l = *(const f16x8*)(B1 + 8);        \
    f16x8 b2l = *(const f16x8*)(B2 + 8), b3l = *(const f16x8*)(B3 + 8);        \
    a0 = MFMA16(ah, b0l, a0);                                                  \
    a1 = MFMA16(ah, b1l, a1);                                                  \
    a2 = MFMA16(ah, b2l, a2);                                                  \
    a3 = MFMA16(ah, b3l, a3);                                                  \
  }

template <bool XPRE>
__global__ void __launch_bounds__(256, 1) recur_kernel(
    const float* __restrict__ x, const float* __restrict__ b_lin,
    const _Float16* __restrict__ xs, const _Float16* __restrict__ wf,
    const _Float16* __restrict__ wl, _Float16* __restrict__ hs, const float* __restrict__ bias,
    float* __restrict__ out, int* __restrict__ bar) {
  const int p = blockIdx.x;
  const int g = p >> 5;                               // XCD swizzle: XCD(p)=p%8 = dt>>2
  const int dt = ((p & 7) << 2) + ((p >> 3) & 3);     // -> blocks sharing wf slices co-locate
  const int tid = threadIdx.x;
  const int l = tid & 63, w = tid >> 6;
  const int l15 = l & 15, q = l >> 4;
  const int r0 = g * 64, R = w * 16;
  const int growA = r0 + R + l15;
  int* cnt = bar + g;
  int* abortf = bar + 4;

  __shared__ _Float16 ys[64 * 128];  // 16KB: y feedback slots, XOR-swizzled
  __shared__ int s_ab;

  const size_t HSTRIDE = (size_t)256 * 16 * 64;
  const int d0 = dt * 16;
  const float bg0 = bias[0 * 512 + d0 + l15];
  const float bg1 = bias[1 * 512 + d0 + l15];
  const float bg2 = bias[2 * 512 + d0 + l15];
  const float bg3 = bias[3 * 512 + d0 + l15];
  const float bl0 = b_lin[0 + l15], bl1 = b_lin[16 + l15];
  const float bl2 = b_lin[32 + l15], bl3 = b_lin[48 + l15];

  const _Float16* wf0 = wf + (size_t)(0 * 32 + dt) * 34816 + (size_t)l * 16;
  const _Float16* wf1 = wf + (size_t)(1 * 32 + dt) * 34816 + (size_t)l * 16;
  const _Float16* wf2 = wf + (size_t)(2 * 32 + dt) * 34816 + (size_t)l * 16;
  const _Float16* wf3 = wf + (size_t)(3 * 32 + dt) * 34816 + (size_t)l * 16;

  const _Float16* hsA = hs + (size_t)growA * 1024 + q * 16;   // + buf*HSTRIDE + ki*64
  const _Float16* xsA = xs + (size_t)growA * 524288 + q * 16; // + t*1024 + ki*64 (XPRE)
  const float* xfA = x + (size_t)growA * 262144 + 4 * q;      // + t*512 + ki*32 (fallback)

  const int kiW = dt >> 1;
  const int jW = (l15 & 3) + 4 * (dt & 1);
  const int hW = l15 >> 2;
  _Float16* hwbase = hs + (((size_t)(r0 + R + 4 * q) * 16 + kiW) * 64 + hW * 16 + jW);

  const f32x4 Z = {0.f, 0.f, 0.f, 0.f};
  f32x4 cst = Z;  // cell state in registers for all 512 steps

  // y-phase: logits = h @ W_lin^T + b_lin (MFMA, hi/lo), softmax, LDS slots (+ out)
  auto yphase = [&](int tcur, const _Float16* hA, bool writeLDS) {
    f32x4 y0 = Z, y1 = Z, y2 = Z, y3 = Z;
#pragma unroll 2
    for (int ki = 0; ki < 16; ++ki) {
      const _Float16* Ap = hA + (size_t)ki * 64;
      f16x8 ah = *(const f16x8*)Ap, al = *(const f16x8*)(Ap + 8);
      const _Float16* B0 = wl + (size_t)ki * 1024 + (size_t)l * 16;
      const _Float16* B1 = B0 + 16384;
      const _Float16* B2 = B0 + 32768;
      const _Float16* B3 = B0 + 49152;
      f16x8 b0h = *(const f16x8*)B0, b1h = *(const f16x8*)B1;
      f16x8 b2h = *(const f16x8*)B2, b3h = *(const f16x8*)B3;
      y0 = MFMA16(ah, b0h, y0);
      y1 = MFMA16(ah, b1h, y1);
      y2 = MFMA16(ah, b2h, y2);
      y3 = MFMA16(ah, b3h, y3);
      y0 = MFMA16(al, b0h, y0);
      y1 = MFMA16(al, b1h, y1);
      y2 = MFMA16(al, b2h, y2);
      y3 = MFMA16(al, b3h, y3);
      f16x8 b0l = *(const f16x8*)(B0 + 8), b1l = *(const f16x8*)(B1 + 8);
      f16x8 b2l = *(const f16x8*)(B2 + 8), b3l = *(const f16x8*)(B3 + 8);
      y0 = MFMA16(ah, b0l, y0);
      y1 = MFMA16(ah, b1l, y1);
      y2 = MFMA16(ah, b2l, y2);
      y3 = MFMA16(ah, b3l, y3);
    }
#pragma unroll
    for (int r = 0; r < 4; ++r) {
      float v0 = y0[r] + bl0, v1 = y1[r] + bl1, v2 = y2[r] + bl2, v3 = y3[r] + bl3;
      float m = fmaxf(fmaxf(v0, v1), fmaxf(v2, v3));
      m = fmaxf(m, __shfl_xor(m, 1));
      m = fmaxf(m, __shfl_xor(m, 2));
      m = fmaxf(m, __shfl_xor(m, 4));
      m = fmaxf(m, __shfl_xor(m, 8));
      float e0 = __expf(v0 - m), e1 = __expf(v1 - m), e2 = __expf(v2 - m), e3 = __expf(v3 - m);
      float s = e0 + e1 + e2 + e3;
      s += __shfl_xor(s, 1);
      s += __shfl_xor(s, 2);
      s += __shfl_xor(s, 4);
      s += __shfl_xor(s, 8);
      float inv = 1.f / s;
      e0 *= inv;
      e1 *= inv;
      e2 *= inv;
      e3 *= inv;
      int rowL = R + 4 * q + r;
      if (writeLDS) {
        int swz = rowL & 7, base = rowL * 128, h2 = l15 >> 2;
        float ev[4] = {e0, e1, e2, e3};
#pragma unroll
        for (int ct = 0; ct < 4; ++ct) {
          _Float16 hh = (_Float16)ev[ct];
          _Float16 ll = (_Float16)(ev[ct] - (float)hh);
          int idx = base + ((((ct >> 1) * 4 + h2) ^ swz) * 16) + (l15 & 3) + 4 * (ct & 1);
          ys[idx] = hh;
          ys[idx + 8] = ll;
        }
      }
      if (dt == 0) {
        size_t ob = (((size_t)(r0 + rowL)) * 512 + tcur) * 64 + l15;
        out[ob] = e0;
        out[ob + 16] = e1;
        out[ob + 32] = e2;
        out[ob + 48] = e3;
      }
    }
  };

#pragma unroll 1
  for (int t = 0; t < 512; ++t) {
    const int rbuf = t & 1, wbuf = rbuf ^ 1;
    const _Float16* hA = hsA + (size_t)rbuf * HSTRIDE;
    if (t > 0) yphase(t - 1, hA, true);
    __syncthreads();  // ys visible to block

    f32x4 a0 = Z, a1 = Z, a2 = Z, a3 = Z;
    if (XPRE) {
      const _Float16* xA = xsA + (size_t)t * 1024;
#pragma unroll 2
      for (int ki = 0; ki < 16; ++ki) {
        const _Float16* Ap = xA + ki * 64;
        f16x8 ah = *(const f16x8*)Ap, al = *(const f16x8*)(Ap + 8);
        GATES_MFMA(ki);
      }
    } else {
      const float* xp = xfA + (size_t)t * 512;
#pragma unroll 2
      for (int ki = 0; ki < 16; ++ki) {
        float4 av = *(const float4*)(xp + ki * 32);
        float4 bv = *(const float4*)(xp + ki * 32 + 16);
        f16x8 ah, al;
        cvt8(av, bv, ah, al);
        GATES_MFMA(ki);
      }
    }
#pragma unroll 2
    for (int ki = 0; ki < 16; ++ki) {
      const _Float16* Ap = hA + ki * 64;
      f16x8 ah = *(const f16x8*)Ap, al = *(const f16x8*)(Ap + 8);
      GATES_MFMA(16 + ki);
    }
    if (t > 0) {
      const int rowL = R + l15, swz = rowL & 7;
#pragma unroll
      for (int kiy = 0; kiy < 2; ++kiy) {
        int idx = rowL * 128 + (((kiy * 4 + q) ^ swz) * 16);
        f16x8 ah = *(const f16x8*)(ys + idx), al = *(const f16x8*)(ys + idx + 8);
        GATES_MFMA(32 + kiy);
      }
    }

    _Float16* hw = hwbase + (size_t)wbuf * HSTRIDE;
#pragma unroll
    for (int r = 0; r < 4; ++r) {
      float zi = a0[r] + bg0, zf = a1[r] + bg1, zg = a2[r] + bg2, zo = a3[r] + bg3;
      float iv = 1.f / (1.f + __expf(-zi));
      float fv = 1.f / (1.f + __expf(-zf));
      float eg = __expf(2.f * zg);
      float gv = 1.f - 2.f / (eg + 1.f);  // tanh, inf-safe
      float ov = 1.f / (1.f + __expf(-zo));
      float cn = fv * cst[r] + iv * gv;
      cst[r] = cn;
      float ec = __expf(2.f * cn);
      float th = 1.f - 2.f / (ec + 1.f);
      float hv = ov * th;
      _Float16 hh = (_Float16)hv;
      _Float16 hl = (_Float16)(hv - (float)hh);
      hw[(size_t)r * 1024] = hh;
      hw[(size_t)r * 1024 + 8] = hl;
    }
    gbar(cnt, abortf, 32 * (t + 1), &s_ab);
    if (s_ab) return;
  }
  if (dt == 0) yphase(511, hsA + (size_t)0 * HSTRIDE, false);  // h_511 is in buffer 0
}

extern "C" void kernel_launch(void* const* d_in, const int* in_sizes, int n_in, void* d_out,
                              int out_size, void* d_ws, size_t ws_size, hipStream_t stream) {
  const float* x = (const float*)d_in[0];
  const float* init_h = (const float*)d_in[1];
  const float* W_ih = (const float*)d_in[2];
  const float* b_ih = (const float*)d_in[3];
  const float* W_hh = (const float*)d_in[4];
  const float* b_hh = (const float*)d_in[5];
  const float* W_lin = (const float*)d_in[6];
  const float* b_lin = (const float*)d_in[7];
  float* out = (float*)d_out;
  (void)in_sizes;
  (void)n_in;
  (void)out_size;

  char* ws = (char*)d_ws;
  size_t off = 0;
  auto take = [&](size_t bytes) -> char* {
    char* r = ws + off;
    off = (off + bytes + 255) & ~(size_t)255;
    return r;
  };
  const size_t WF_E = (size_t)128 * 34 * 64 * 16;  // 4,456,448 f16
  const size_t WL_E = (size_t)4 * 16 * 64 * 16;    // 65,536
  const size_t HS_E = (size_t)2 * 256 * 16 * 64;   // 524,288 (double-buffered)
  const size_t XS_E = (size_t)256 * 512 * 16 * 64; // 134,217,728

  _Float16* wf = (_Float16*)take(WF_E * 2);
  _Float16* wl = (_Float16*)take(WL_E * 2);
  _Float16* hs = (_Float16*)take(HS_E * 2);
  float* bias = (float*)take(2048 * 4);
  int* bar = (int*)take(8 * 4);
  if (ws_size < off) return;  // cannot run at all -> visible failure
  _Float16* xs = (_Float16*)(ws + off);
  const bool xpre = (ws_size >= off + XS_E * 2);

  if (xpre) {
    const int total = 8388608 + 278528 + 4096 + 16384 + 2048 + 8;
    prep_kernel<true><<<(total + 255) / 256, 256, 0, stream>>>(x, init_h, W_ih, b_ih, W_hh, b_hh,
                                                               W_lin, xs, wf, wl, hs, bias, bar);
    recur_kernel<true><<<128, 256, 0, stream>>>(x, b_lin, xs, wf, wl, hs, bias, out, bar);
  } else {
    const int total = 278528 + 4096 + 16384 + 2048 + 8;
    prep_kernel<false><<<(total + 255) / 256, 256, 0, stream>>>(x, init_h, W_ih, b_ih, W_hh, b_hh,
                                                                W_lin, xs, wf, wl, hs, bias, bar);
    recur_kernel<false><<<128, 256, 0, stream>>>(x, b_lin, xs, wf, wl, hs, bias, out, bar);
  }
}